// Round 2
// baseline (37.172 us; speedup 1.0000x reference)
//
#include <hip/hip_runtime.h>
#include <stdint.h>

// MaxSimLoss: anchor [256,64,128] f32, pos/neg [256,512,128] f32 -> scalar f32.
// Memory-bound (142 MB, floor ~23 us). bf16 MFMA for the 2.15G-MAC sim matrix.

#define MARGIN_F 0.1f

typedef __attribute__((ext_vector_type(8))) short short8;   // 8 bf16 (4 VGPRs)
typedef __attribute__((ext_vector_type(4))) float floatx4;  // 4 f32 acc

// f32 -> bf16 round-to-nearest-even (inputs finite)
__device__ __forceinline__ unsigned short f2bf(float f) {
  union { float f; uint32_t u; } x; x.f = f;
  uint32_t u = x.u;
  return (unsigned short)((u + 0x7FFFu + ((u >> 16) & 1u)) >> 16);
}

// Swizzled byte offset for element (row, colbyte) in a [64][256B] bf16 LDS tile.
// XOR of bits 4-6 breaks the row-stride-256B bank pattern (G4); preserves
// 16B-alignment so ds_read_b128 / ds_write_b64 stay legal. Applied on BOTH
// the ds_write (staging) and ds_read (fragment) sides.
__device__ __forceinline__ int swz(int row, int colbyte) {
  return (row * 256 + colbyte) ^ ((row & 7) << 4);
}

// Issue 8 float4 loads covering a 64x128 f32 tile (row = i*8 + tid>>5,
// 4KB contiguous per instruction across 256 threads -> fully coalesced).
__device__ __forceinline__ void issue8(const float* __restrict__ src, int tid,
                                       float4 (&v)[8]) {
#pragma unroll
  for (int i = 0; i < 8; ++i)
    v[i] = *reinterpret_cast<const float4*>(src + i * 1024 + tid * 4);
}

// Convert the staged tile to bf16 LDS (swizzled) + per-row inverse norms.
// Each 32-lane group owns one full row per iteration -> shfl butterfly sums it.
__device__ __forceinline__ void process8(const float4 (&v)[8],
                                         char* __restrict__ tileBytes,
                                         float* __restrict__ inv, int tid) {
  int lane32 = tid & 31;
  int rb = tid >> 5;
#pragma unroll
  for (int i = 0; i < 8; ++i) {
    int row = i * 8 + rb;
    float4 t = v[i];
    float ss = t.x * t.x + t.y * t.y + t.z * t.z + t.w * t.w;
    ss += __shfl_xor(ss, 1);
    ss += __shfl_xor(ss, 2);
    ss += __shfl_xor(ss, 4);
    ss += __shfl_xor(ss, 8);
    ss += __shfl_xor(ss, 16);
    if (lane32 == 0) inv[row] = 1.0f / fmaxf(sqrtf(ss), 1e-12f);
    ushort4 u;
    u.x = f2bf(t.x); u.y = f2bf(t.y); u.z = f2bf(t.z); u.w = f2bf(t.w);
    *reinterpret_cast<ushort4*>(tileBytes + swz(row, lane32 * 8)) = u;
  }
}

// One block per (batch, side). 256 threads = 4 waves; wave w owns t-rows
// [16w, 16w+16). Streams 8 chunks of 64 s-rows with register ping-pong
// prefetch; 16 MFMAs (16x16x32 bf16) per wave per chunk.
__global__ __launch_bounds__(256, 2) void maxsim_kernel(
    const float* __restrict__ anchor, const float* __restrict__ pos,
    const float* __restrict__ neg, float* __restrict__ scores) {
  __shared__ alignas(16) char sA[64 * 256];  // anchor tile, bf16 swizzled
  __shared__ alignas(16) char sB[64 * 256];  // s-chunk tile, bf16 swizzled
  __shared__ float sInvA[64];
  __shared__ float sInvB[64];
  __shared__ float sWaveSum[4];

  int bs = blockIdx.x;
  int b = bs >> 1;
  int side = bs & 1;
  const float* base = (side ? neg : pos) + (size_t)b * 512 * 128;
  const float* abase = anchor + (size_t)b * 64 * 128;

  int tid = threadIdx.x;
  int lane = tid & 63;
  int wid = tid >> 6;

  // Stage anchor (once per block).
  {
    float4 v[8];
    issue8(abase, tid, v);
    process8(v, sA, sInvA, tid);
  }
  __syncthreads();

  // Preload A fragments for this wave's t-tile (reused for all 8 chunks).
  // Frag pattern: lane holds row (lane&15), 8 consecutive k at (lane>>4)*8,
  // per k-step of 32. Same pattern for B -> mfma computes A*B^T (sim tile).
  short8 aF[4];
  {
    int arow = wid * 16 + (lane & 15);
    int colb = (lane >> 4) * 16;
#pragma unroll
    for (int k = 0; k < 4; ++k)
      aF[k] = *reinterpret_cast<const short8*>(sA + swz(arow, colb + k * 64));
  }

  float rmax[4] = {-1e30f, -1e30f, -1e30f, -1e30f};

  float4 buf[2][8];  // fully unrolled chunk loop -> static indexing (rule #20)
  issue8(base, tid, buf[0]);

#pragma unroll
  for (int c = 0; c < 8; ++c) {
    int cur = c & 1;
    if (c < 7) issue8(base + (size_t)(c + 1) * 64 * 128, tid, buf[cur ^ 1]);
    __syncthreads();  // prior MFMA phase done reading sB/sInvB
    process8(buf[cur], sB, sInvB, tid);
    __syncthreads();

#pragma unroll
    for (int st = 0; st < 4; ++st) {
      int brow = st * 16 + (lane & 15);
      int colb = (lane >> 4) * 16;
      short8 bF[4];
#pragma unroll
      for (int k = 0; k < 4; ++k)
        bF[k] = *reinterpret_cast<const short8*>(sB + swz(brow, colb + k * 64));
      floatx4 acc = {0.f, 0.f, 0.f, 0.f};
#pragma unroll
      for (int k = 0; k < 4; ++k)
        acc = __builtin_amdgcn_mfma_f32_16x16x32_bf16(aF[k], bF[k], acc, 0, 0, 0);
      // D layout: row(t) = (lane>>4)*4 + j, col(s) = lane&15 (+ tile bases).
      float invb = sInvB[st * 16 + (lane & 15)];
#pragma unroll
      for (int j = 0; j < 4; ++j)
        rmax[j] = fmaxf(rmax[j], acc[j] * invb);
    }
  }

  // rmax[j] = max over s in {s : s%16 == lane&15} for t = wid*16+(lane>>4)*4+j.
  // Butterfly-max over lane bits 0-3 completes max over all 512 s.
#pragma unroll
  for (int j = 0; j < 4; ++j) {
    float m = rmax[j];
    m = fmaxf(m, __shfl_xor(m, 1));
    m = fmaxf(m, __shfl_xor(m, 2));
    m = fmaxf(m, __shfl_xor(m, 4));
    m = fmaxf(m, __shfl_xor(m, 8));
    rmax[j] = m;
  }
  int g = lane >> 4;
  float tsum = 0.f;
#pragma unroll
  for (int j = 0; j < 4; ++j)
    tsum += rmax[j] * sInvA[wid * 16 + g * 4 + j];
  // Sum the 4 lane-groups (each group's tsum is uniform across its 16 lanes).
  tsum += __shfl_xor(tsum, 16);
  tsum += __shfl_xor(tsum, 32);
  if (lane == 0) sWaveSum[wid] = tsum;
  __syncthreads();
  if (tid == 0)
    scores[bs] =
        (sWaveSum[0] + sWaveSum[1] + sWaveSum[2] + sWaveSum[3]) * (1.0f / 64.0f);
}

// scores[2b] = pos_score, scores[2b+1] = neg_score. Hinge + mean, one block.
__global__ void hinge_reduce_kernel(const float* __restrict__ scores,
                                    float* __restrict__ out) {
  int tid = threadIdx.x;  // 256 threads, one per batch
  float p = scores[2 * tid];
  float n = scores[2 * tid + 1];
  float h = fmaxf(MARGIN_F + n - p, 0.0f);
  h += __shfl_xor(h, 1);
  h += __shfl_xor(h, 2);
  h += __shfl_xor(h, 4);
  h += __shfl_xor(h, 8);
  h += __shfl_xor(h, 16);
  h += __shfl_xor(h, 32);
  __shared__ float sw[4];
  if ((tid & 63) == 0) sw[tid >> 6] = h;
  __syncthreads();
  if (tid == 0) out[0] = (sw[0] + sw[1] + sw[2] + sw[3]) * (1.0f / 256.0f);
}

extern "C" void kernel_launch(void* const* d_in, const int* in_sizes, int n_in,
                              void* d_out, int out_size, void* d_ws,
                              size_t ws_size, hipStream_t stream) {
  const float* anchor = (const float*)d_in[0];
  const float* pos = (const float*)d_in[1];
  const float* neg = (const float*)d_in[2];
  float* scores = (float*)d_ws;  // 512 floats
  maxsim_kernel<<<dim3(512), dim3(256), 0, stream>>>(anchor, pos, neg, scores);
  hinge_reduce_kernel<<<dim3(1), dim3(256), 0, stream>>>(scores, (float*)d_out);
}

// Round 3
// 36.753 us; speedup vs baseline: 1.0114x; 1.0114x over previous
//
#include <hip/hip_runtime.h>
#include <stdint.h>

// MaxSimLoss: anchor [256,64,128] f32, pos/neg [256,512,128] f32 -> scalar f32.
// Memory-bound (~142 MB, HBM floor ~23 us). Barrier-free main loop: MFMA
// fragments are loaded straight from global in fragment layout (L1 absorbs
// the strided segments), norms computed in-register (2 shuffles), bf16 MFMA
// for the sim matrix. R2 post-mortem: LDS-staged version was lockstep-bound
// (VALUBusy 11%, MfmaUtil 1.4%, all pipes idle at 37 us).

#define MARGIN_F 0.1f

typedef __attribute__((ext_vector_type(8))) short short8;   // 8 bf16
typedef __attribute__((ext_vector_type(4))) float floatx4;  // 4 f32 acc

// f32 -> bf16 round-to-nearest-even (inputs finite); same as R2 (absmax 0.0).
__device__ __forceinline__ unsigned short f2bf(float f) {
  union { float f; uint32_t u; } x; x.f = f;
  uint32_t u = x.u;
  return (unsigned short)((u + 0x7FFFu + ((u >> 16) & 1u)) >> 16);
}

__device__ __forceinline__ short8 pack8(float4 a, float4 b) {
  short8 r;
  r[0] = (short)f2bf(a.x); r[1] = (short)f2bf(a.y);
  r[2] = (short)f2bf(a.z); r[3] = (short)f2bf(a.w);
  r[4] = (short)f2bf(b.x); r[5] = (short)f2bf(b.y);
  r[6] = (short)f2bf(b.z); r[7] = (short)f2bf(b.w);
  return r;
}

__device__ __forceinline__ float sq4(float4 a) {
  return a.x * a.x + a.y * a.y + a.z * a.z + a.w * a.w;
}

// One block per (batch, side); 4 waves partition s (128 rows each).
// Fragment pattern (verified in R2): lane holds row (lane&15), elements
// (lane>>4)*8 + k*32 .. +8 per k-slice; identical for A and B -> D = A.B^T
// with row(t) = (lane>>4)*4 + j, col(s) = lane&15.
__global__ __launch_bounds__(256, 2) void maxsim_kernel(
    const float* __restrict__ anchor, const float* __restrict__ pos,
    const float* __restrict__ neg, float* __restrict__ scores) {
  __shared__ float sInvA[64];
  __shared__ float sPart[4][64];

  int bs = blockIdx.x;
  int b = bs >> 1;
  int side = bs & 1;
  const float* base = (side ? neg : pos) + (size_t)b * 512 * 128;
  const float* abase = anchor + (size_t)b * 64 * 128;

  int tid = threadIdx.x;
  int lane = tid & 63;
  int wid = tid >> 6;
  int r = lane & 15;   // fragment row within subtile / accumulator col
  int g = lane >> 4;   // k-group (elements g*8 + k*32)

  // --- A: all 4 t-subtiles into registers, norms in-register. ---
  short8 aF[4][4];
#pragma unroll
  for (int tst = 0; tst < 4; ++tst) {
    const float* arow = abase + (size_t)(tst * 16 + r) * 128 + g * 8;
    float ss = 0.f;
#pragma unroll
    for (int k = 0; k < 4; ++k) {
      float4 v0 = *reinterpret_cast<const float4*>(arow + k * 32);
      float4 v1 = *reinterpret_cast<const float4*>(arow + k * 32 + 4);
      ss += sq4(v0) + sq4(v1);
      aF[tst][k] = pack8(v0, v1);
    }
    // 4 lane-groups hold this row's 4 quarters -> 2-shuffle sum.
    ss += __shfl_xor(ss, 16);
    ss += __shfl_xor(ss, 32);
    if (g == 0) sInvA[tst * 16 + r] = 1.0f / fmaxf(sqrtf(ss), 1e-12f);
  }
  __syncthreads();  // sInvA ready; last sync until epilogue

  // --- Main loop: 8 s-subtiles of 16 rows per wave, barrier-free, ---
  // --- depth-1 register prefetch (8 KB in flight per wave).       ---
  const float* sbase = base + (size_t)wid * 128 * 128;
  float rmax[4][4];
#pragma unroll
  for (int tst = 0; tst < 4; ++tst)
#pragma unroll
    for (int j = 0; j < 4; ++j) rmax[tst][j] = -1e30f;

  float4 buf[2][8];  // fully unrolled -> static indexing (rule #20)
#pragma unroll
  for (int k = 0; k < 4; ++k) {
    const float* p = sbase + (size_t)r * 128 + g * 8 + k * 32;
    buf[0][2 * k] = *reinterpret_cast<const float4*>(p);
    buf[0][2 * k + 1] = *reinterpret_cast<const float4*>(p + 4);
  }

#pragma unroll
  for (int i = 0; i < 8; ++i) {
    int cur = i & 1;
    if (i < 7) {
      const float* p =
          sbase + (size_t)((i + 1) * 16 + r) * 128 + g * 8;
#pragma unroll
      for (int k = 0; k < 4; ++k) {
        buf[cur ^ 1][2 * k] = *reinterpret_cast<const float4*>(p + k * 32);
        buf[cur ^ 1][2 * k + 1] =
            *reinterpret_cast<const float4*>(p + k * 32 + 4);
      }
    }
    // Row norm for this lane's loaded row (s = wid*128 + i*16 + r).
    float ss = 0.f;
#pragma unroll
    for (int k = 0; k < 8; ++k) ss += sq4(buf[cur][k]);
    ss += __shfl_xor(ss, 16);
    ss += __shfl_xor(ss, 32);
    float invb = 1.0f / fmaxf(sqrtf(ss), 1e-12f);

    short8 bF[4];
#pragma unroll
    for (int k = 0; k < 4; ++k)
      bF[k] = pack8(buf[cur][2 * k], buf[cur][2 * k + 1]);

    floatx4 acc[4] = {{0.f, 0.f, 0.f, 0.f},
                      {0.f, 0.f, 0.f, 0.f},
                      {0.f, 0.f, 0.f, 0.f},
                      {0.f, 0.f, 0.f, 0.f}};
#pragma unroll
    for (int k = 0; k < 4; ++k)
#pragma unroll
      for (int tst = 0; tst < 4; ++tst)
        acc[tst] =
            __builtin_amdgcn_mfma_f32_16x16x32_bf16(aF[tst][k], bF[k], acc[tst], 0, 0, 0);
    // acc[tst][j]: row t = tst*16 + g*4 + j, col s-rel = lane&15.
    // invb for col r is this lane's own invb (it loaded row i*16 + r).
#pragma unroll
    for (int tst = 0; tst < 4; ++tst)
#pragma unroll
      for (int j = 0; j < 4; ++j)
        rmax[tst][j] = fmaxf(rmax[tst][j], acc[tst][j] * invb);
  }

  // Butterfly-max over cols (lane bits 0-3) -> per-t max over wave's s-range.
#pragma unroll
  for (int tst = 0; tst < 4; ++tst)
#pragma unroll
    for (int j = 0; j < 4; ++j) {
      float m = rmax[tst][j];
      m = fmaxf(m, __shfl_xor(m, 1));
      m = fmaxf(m, __shfl_xor(m, 2));
      m = fmaxf(m, __shfl_xor(m, 4));
      m = fmaxf(m, __shfl_xor(m, 8));
      rmax[tst][j] = m;  // t = tst*16 + g*4 + j, uniform over lane bits 0-3
    }
  if (r == 0) {
#pragma unroll
    for (int tst = 0; tst < 4; ++tst)
#pragma unroll
      for (int j = 0; j < 4; ++j)
        sPart[wid][tst * 16 + g * 4 + j] = rmax[tst][j];
  }
  __syncthreads();
  if (tid < 64) {
    float m = fmaxf(fmaxf(sPart[0][tid], sPart[1][tid]),
                    fmaxf(sPart[2][tid], sPart[3][tid]));
    float val = m * sInvA[tid];
    val += __shfl_xor(val, 1);
    val += __shfl_xor(val, 2);
    val += __shfl_xor(val, 4);
    val += __shfl_xor(val, 8);
    val += __shfl_xor(val, 16);
    val += __shfl_xor(val, 32);
    if (tid == 0) scores[bs] = val * (1.0f / 64.0f);
  }
}

// scores[2b] = pos_score, scores[2b+1] = neg_score. Hinge + mean, one block.
__global__ void hinge_reduce_kernel(const float* __restrict__ scores,
                                    float* __restrict__ out) {
  int tid = threadIdx.x;  // 256 threads, one per batch
  float p = scores[2 * tid];
  float n = scores[2 * tid + 1];
  float h = fmaxf(MARGIN_F + n - p, 0.0f);
  h += __shfl_xor(h, 1);
  h += __shfl_xor(h, 2);
  h += __shfl_xor(h, 4);
  h += __shfl_xor(h, 8);
  h += __shfl_xor(h, 16);
  h += __shfl_xor(h, 32);
  __shared__ float sw[4];
  if ((tid & 63) == 0) sw[tid >> 6] = h;
  __syncthreads();
  if (tid == 0) out[0] = (sw[0] + sw[1] + sw[2] + sw[3]) * (1.0f / 256.0f);
}

extern "C" void kernel_launch(void* const* d_in, const int* in_sizes, int n_in,
                              void* d_out, int out_size, void* d_ws,
                              size_t ws_size, hipStream_t stream) {
  const float* anchor = (const float*)d_in[0];
  const float* pos = (const float*)d_in[1];
  const float* neg = (const float*)d_in[2];
  float* scores = (float*)d_ws;  // 512 floats
  maxsim_kernel<<<dim3(512), dim3(256), 0, stream>>>(anchor, pos, neg, scores);
  hinge_reduce_kernel<<<dim3(1), dim3(256), 0, stream>>>(scores, (float*)d_out);
}